// Round 1
// baseline (584.363 us; speedup 1.0000x reference)
//
#include <hip/hip_runtime.h>
#include <hip/hip_fp16.h>

#define B_ 2
#define L_ 2048
#define D_ 2048
#define H_ 16
#define DH_ 128

typedef _Float16 f16;
typedef _Float16 f16x8 __attribute__((ext_vector_type(8)));
typedef _Float16 f16x4 __attribute__((ext_vector_type(4)));
typedef _Float16 f16x2 __attribute__((ext_vector_type(2)));
typedef float f32x4 __attribute__((ext_vector_type(4)));

__device__ __forceinline__ void gload_lds16(const void* g, void* l) {
  __builtin_amdgcn_global_load_lds(
      (__attribute__((address_space(1))) void*)(void*)g,
      (__attribute__((address_space(3))) void*)l, 16, 0, 0);
}

__device__ __forceinline__ float rmax16(float v) {
  v = fmaxf(v, __shfl_xor(v, 1));
  v = fmaxf(v, __shfl_xor(v, 2));
  v = fmaxf(v, __shfl_xor(v, 4));
  v = fmaxf(v, __shfl_xor(v, 8));
  return v;
}
__device__ __forceinline__ float rsum16(float v) {
  v += __shfl_xor(v, 1);
  v += __shfl_xor(v, 2);
  v += __shfl_xor(v, 4);
  v += __shfl_xor(v, 8);
  return v;
}

// ---------------- kernel 1: cast x fp32 -> fp16 ----------------
__global__ __launch_bounds__(256) void k_cast(const float* __restrict__ in,
                                              f16* __restrict__ out, int n8) {
  int i = blockIdx.x * blockDim.x + threadIdx.x;
  if (i >= n8) return;
  const float4* p = (const float4*)in + (size_t)i * 2;
  float4 a = p[0], b = p[1];
  f16x8 o;
  o[0] = (f16)a.x; o[1] = (f16)a.y; o[2] = (f16)a.z; o[3] = (f16)a.w;
  o[4] = (f16)b.x; o[5] = (f16)b.y; o[6] = (f16)b.z; o[7] = (f16)b.w;
  *((f16x8*)out + i) = o;
}

// ------- kernel 2: transpose+cast 2048x2048 fp32 -> fp16 (N x K) -------
__global__ __launch_bounds__(256) void k_transpose4(
    const float* __restrict__ W0, const float* __restrict__ W1,
    const float* __restrict__ W2, const float* __restrict__ W3,
    f16* __restrict__ T0, f16* __restrict__ T1, f16* __restrict__ T2,
    f16* __restrict__ T3) {
  int z = blockIdx.z;
  const float* src = (z == 0) ? W0 : (z == 1) ? W1 : (z == 2) ? W2 : W3;
  f16* dst = (z == 0) ? T0 : (z == 1) ? T1 : (z == 2) ? T2 : T3;
  __shared__ float tile[32][33];
  int tx = threadIdx.x, ty = threadIdx.y;
  int x = blockIdx.x * 32 + tx;
  int y0 = blockIdx.y * 32;
#pragma unroll
  for (int i = 0; i < 4; ++i)
    tile[ty + i * 8][tx] = src[(size_t)(y0 + ty + i * 8) * 2048 + x];
  __syncthreads();
  int ox = y0 + tx;               // k index in output
  int oy0 = blockIdx.x * 32;      // n base
#pragma unroll
  for (int i = 0; i < 4; ++i)
    dst[(size_t)(oy0 + ty + i * 8) * 2048 + ox] = (f16)tile[tx][ty + i * 8];
}

// ---------------- shared GEMM core: 128x128 tile, BK=32 ----------------
// A: M x K fp16 row-major.  BT: N x K fp16 row-major.  K = 2048.
__device__ __forceinline__ void gemm_core(const f16* __restrict__ A,
                                          const f16* __restrict__ BT,
                                          f16* As, f16* Bs, int m0, int n0,
                                          f32x4 (&acc)[4][4]) {
  const int tid = threadIdx.x;
  const int lane = tid & 63, w = tid >> 6;
  const int wr = w >> 1, wc = w & 1;
  const int li = lane & 15, lg = lane >> 4;
  for (int kt = 0; kt < 64; ++kt) {
    __syncthreads();
#pragma unroll
    for (int p = 0; p < 2; ++p) {
      int o = tid * 16 + p * 4096;      // byte offset into 8KB tile
      int row = o >> 6, cb = o & 63;    // 64B per row (32 halfs)
      gload_lds16((const char*)A + (size_t)(m0 + row) * 4096 + kt * 64 + cb,
                  (char*)As + o);
      gload_lds16((const char*)BT + (size_t)(n0 + row) * 4096 + kt * 64 + cb,
                  (char*)Bs + o);
    }
    __syncthreads();
    f16x8 af[4], bf[4];
#pragma unroll
    for (int i = 0; i < 4; ++i) {
      af[i] = *(const f16x8*)(As + (wr * 64 + i * 16 + li) * 32 + lg * 8);
      bf[i] = *(const f16x8*)(Bs + (wc * 64 + i * 16 + li) * 32 + lg * 8);
    }
#pragma unroll
    for (int i = 0; i < 4; ++i)
#pragma unroll
      for (int j = 0; j < 4; ++j)
        acc[i][j] =
            __builtin_amdgcn_mfma_f32_16x16x32_f16(af[i], bf[j], acc[i][j], 0, 0, 0);
  }
}

// --------- kernel 3: QKV projection, epilogues write q/k head-major, v transposed ---------
__global__ __launch_bounds__(256) void k_gemm_qkv(
    const f16* __restrict__ x16, const f16* __restrict__ WqT,
    const f16* __restrict__ WkT, const f16* __restrict__ WvT,
    f16* __restrict__ qh, f16* __restrict__ kh, f16* __restrict__ vTo) {
  __shared__ alignas(16) f16 As[128 * 32];
  __shared__ alignas(16) f16 Bs[128 * 32];
  const int z = blockIdx.z;
  const f16* BT = (z == 0) ? WqT : (z == 1) ? WkT : WvT;
  const int m0 = blockIdx.y * 128, n0 = blockIdx.x * 128;
  f32x4 acc[4][4] = {};
  gemm_core(x16, BT, As, Bs, m0, n0, acc);
  const int lane = threadIdx.x & 63, w = threadIdx.x >> 6;
  const int wr = w >> 1, wc = w & 1, li = lane & 15, lg = lane >> 4;
  if (z < 2) {
    f16* out = (z == 0) ? qh : kh;
#pragma unroll
    for (int i = 0; i < 4; ++i) {
      int mb = m0 + wr * 64 + i * 16 + lg * 4;
#pragma unroll
      for (int j = 0; j < 4; ++j) {
        int n = n0 + wc * 64 + j * 16 + li;
        int h = n >> 7, dh = n & 127;
#pragma unroll
        for (int r = 0; r < 4; ++r) {
          int m = mb + r;
          int b = m >> 11, l = m & 2047;
          out[(((size_t)(b * 16 + h) * 2048 + l) << 7) + dh] = (f16)acc[i][j][r];
        }
      }
    }
  } else {
#pragma unroll
    for (int i = 0; i < 4; ++i) {
      int mb = m0 + wr * 64 + i * 16 + lg * 4;  // multiple of 4
      int b = mb >> 11, l = mb & 2047;
#pragma unroll
      for (int j = 0; j < 4; ++j) {
        int n = n0 + wc * 64 + j * 16 + li;
        int h = n >> 7, dh = n & 127;
        f16x4 v4;
#pragma unroll
        for (int r = 0; r < 4; ++r) v4[r] = (f16)acc[i][j][r];
        *(f16x4*)(vTo + ((size_t)(b * 16 + h) * 128 + dh) * 2048 + l) = v4;
      }
    }
  }
}

// ---------------- kernel 4: RoPE + L2 normalize, in place on qh/kh ----------------
// one wave per (b,h,l) row; lane i owns pair (2i, 2i+1)
__global__ __launch_bounds__(256) void k_rope_norm(f16* __restrict__ qh,
                                                   f16* __restrict__ kh) {
  int gid = blockIdx.x * 4 + (threadIdx.x >> 6);  // 0 .. 131071
  int lane = threadIdx.x & 63;
  int which = gid >> 16;
  int r = gid & 65535;          // (b*16+h)*2048 + l
  int l = r & 2047;
  f16* base = (which ? kh : qh) + (size_t)r * 128;
  f16x2 xv = *(f16x2*)(base + lane * 2);
  float x0 = (float)xv[0], x1 = (float)xv[1];
  // inv_freq = theta^(-lane/64) = exp2(-lane * log2(500000)/64)
  float invf = exp2f(-(float)lane * 0.29580575889569f);
  float ang = (float)l * invf;
  float s, c;
  sincosf(ang, &s, &c);
  float y0 = x0 * c - x1 * s;
  float y1 = x1 * c + x0 * s;
  float ss = y0 * y0 + y1 * y1;
  ss += __shfl_xor(ss, 1);  ss += __shfl_xor(ss, 2);
  ss += __shfl_xor(ss, 4);  ss += __shfl_xor(ss, 8);
  ss += __shfl_xor(ss, 16); ss += __shfl_xor(ss, 32);
  float inv = 1.0f / (sqrtf(ss) + 1e-6f);
  f16x2 o;
  o[0] = (f16)(y0 * inv);
  o[1] = (f16)(y1 * inv);
  *(f16x2*)(base + lane * 2) = o;
}

// ---------------- kernel 5: flash attention (causal) ----------------
// grid.x = 16 q-tiles of 128, grid.y = B*H = 32. 4 waves, 32 q-rows each.
__global__ __launch_bounds__(256) void k_flash(
    const f16* __restrict__ qh, const f16* __restrict__ kh,
    const f16* __restrict__ vT, f16* __restrict__ attO,
    const float* __restrict__ ascale_p) {
  const int bh = blockIdx.y;
  const int q0 = blockIdx.x * 128;
  const int tid = threadIdx.x, lane = tid & 63, w = tid >> 6;
  const int li = lane & 15, lg = lane >> 4;
  const float csc = ascale_p[0] * 1.44269504088896f;  // attn_scale * log2(e)

  __shared__ alignas(16) f16 Ks[64 * 136];
  __shared__ alignas(16) f16 Vs[128 * 72];
  __shared__ alignas(16) f16 Ps[4][32 * 72];

  const f16* qb = qh + (size_t)bh * 2048 * 128;
  const f16* kb = kh + (size_t)bh * 2048 * 128;
  const f16* vb = vT + (size_t)bh * 128 * 2048;

  const int qw = q0 + w * 32;

  f16x8 Qr[2][4];
#pragma unroll
  for (int qf = 0; qf < 2; ++qf)
#pragma unroll
    for (int ks = 0; ks < 4; ++ks)
      Qr[qf][ks] =
          *(const f16x8*)(qb + (size_t)(qw + qf * 16 + li) * 128 + ks * 32 + lg * 8);

  f32x4 Oa[2][8] = {};
  float mrow[2][4], lrow[2][4];
#pragma unroll
  for (int qf = 0; qf < 2; ++qf)
#pragma unroll
    for (int r = 0; r < 4; ++r) { mrow[qf][r] = -1e30f; lrow[qf][r] = 0.0f; }

  const int ntiles = (blockIdx.x + 1) * 2;
  for (int kt = 0; kt < ntiles; ++kt) {
    const int k0 = kt * 64;
    __syncthreads();
    // stage K (64x128) and VT (128x64) tiles into padded LDS
#pragma unroll
    for (int p = 0; p < 4; ++p) {
      int e = (p * 256 + tid) * 8;
      int row = e >> 7, col = e & 127;
      *(f16x8*)(Ks + row * 136 + col) =
          *(const f16x8*)(kb + (size_t)(k0 + row) * 128 + col);
      int row2 = e >> 6, col2 = e & 63;
      *(f16x8*)(Vs + row2 * 72 + col2) =
          *(const f16x8*)(vb + (size_t)row2 * 2048 + k0 + col2);
    }
    __syncthreads();

    // S = Q K^T   (32 q-rows x 64 k-cols per wave)
    f32x4 Sa[2][4] = {};
#pragma unroll
    for (int ks = 0; ks < 4; ++ks) {
      f16x8 kf4[4];
#pragma unroll
      for (int kf = 0; kf < 4; ++kf)
        kf4[kf] = *(const f16x8*)(Ks + (kf * 16 + li) * 136 + ks * 32 + lg * 8);
#pragma unroll
      for (int qf = 0; qf < 2; ++qf)
#pragma unroll
        for (int kf = 0; kf < 4; ++kf)
          Sa[qf][kf] = __builtin_amdgcn_mfma_f32_16x16x32_f16(Qr[qf][ks], kf4[kf],
                                                              Sa[qf][kf], 0, 0, 0);
    }
    // causal mask
    if (k0 + 63 > qw) {
#pragma unroll
      for (int qf = 0; qf < 2; ++qf)
#pragma unroll
        for (int kf = 0; kf < 4; ++kf)
#pragma unroll
          for (int r = 0; r < 4; ++r) {
            int qq = qw + qf * 16 + lg * 4 + r;
            int kk = k0 + kf * 16 + li;
            if (kk > qq) Sa[qf][kf][r] = -1e30f;
          }
    }
    // online softmax (rows live in 16-lane groups)
#pragma unroll
    for (int qf = 0; qf < 2; ++qf) {
#pragma unroll
      for (int r = 0; r < 4; ++r) {
        float v = fmaxf(fmaxf(Sa[qf][0][r], Sa[qf][1][r]),
                        fmaxf(Sa[qf][2][r], Sa[qf][3][r]));
        v = rmax16(v);
        float mold = mrow[qf][r];
        float mnew = fmaxf(mold, v);
        float scale = exp2f(csc * (mold - mnew));
        mrow[qf][r] = mnew;
        float rs = 0.0f;
#pragma unroll
        for (int kf = 0; kf < 4; ++kf) {
          float p = exp2f(csc * (Sa[qf][kf][r] - mnew));
          Sa[qf][kf][r] = p;
          rs += p;
        }
        rs = rsum16(rs);
        lrow[qf][r] = lrow[qf][r] * scale + rs;
#pragma unroll
        for (int df = 0; df < 8; ++df) Oa[qf][df][r] *= scale;
      }
    }
    // P -> LDS (per-wave buffer), then PV
    f16* Pw = &Ps[w][0];
#pragma unroll
    for (int qf = 0; qf < 2; ++qf)
#pragma unroll
      for (int kf = 0; kf < 4; ++kf)
#pragma unroll
        for (int r = 0; r < 4; ++r)
          Pw[(qf * 16 + lg * 4 + r) * 72 + kf * 16 + li] = (f16)Sa[qf][kf][r];
    asm volatile("s_waitcnt lgkmcnt(0)" ::: "memory");
    __builtin_amdgcn_sched_barrier(0);
#pragma unroll
    for (int k2 = 0; k2 < 2; ++k2) {
      f16x8 pa[2], vfr[8];
#pragma unroll
      for (int qf = 0; qf < 2; ++qf)
        pa[qf] = *(const f16x8*)(Pw + (qf * 16 + li) * 72 + k2 * 32 + lg * 8);
#pragma unroll
      for (int df = 0; df < 8; ++df)
        vfr[df] = *(const f16x8*)(Vs + (df * 16 + li) * 72 + k2 * 32 + lg * 8);
#pragma unroll
      for (int qf = 0; qf < 2; ++qf)
#pragma unroll
        for (int df = 0; df < 8; ++df)
          Oa[qf][df] = __builtin_amdgcn_mfma_f32_16x16x32_f16(pa[qf], vfr[df],
                                                              Oa[qf][df], 0, 0, 0);
    }
  }
  // epilogue: O /= l, write (B,L,H*Dh) fp16
  const int b = bh >> 4, h = bh & 15;
#pragma unroll
  for (int qf = 0; qf < 2; ++qf)
#pragma unroll
    for (int r = 0; r < 4; ++r) {
      float inv = 1.0f / lrow[qf][r];
      int q = qw + qf * 16 + lg * 4 + r;
      f16* orow = attO + (size_t)(b * 2048 + q) * 2048 + h * 128;
#pragma unroll
      for (int df = 0; df < 8; ++df)
        orow[df * 16 + li] = (f16)(Oa[qf][df][r] * inv);
    }
}

// ---------------- kernel 6: output projection -> fp32 ----------------
__global__ __launch_bounds__(256) void k_gemm_out(const f16* __restrict__ A,
                                                  const f16* __restrict__ WoutT,
                                                  float* __restrict__ out) {
  __shared__ alignas(16) f16 As[128 * 32];
  __shared__ alignas(16) f16 Bs[128 * 32];
  const int m0 = blockIdx.y * 128, n0 = blockIdx.x * 128;
  f32x4 acc[4][4] = {};
  gemm_core(A, WoutT, As, Bs, m0, n0, acc);
  const int lane = threadIdx.x & 63, w = threadIdx.x >> 6;
  const int wr = w >> 1, wc = w & 1, li = lane & 15, lg = lane >> 4;
#pragma unroll
  for (int i = 0; i < 4; ++i)
#pragma unroll
    for (int j = 0; j < 4; ++j) {
      int n = n0 + wc * 64 + j * 16 + li;
#pragma unroll
      for (int r = 0; r < 4; ++r) {
        int m = m0 + wr * 64 + i * 16 + lg * 4 + r;
        out[(size_t)m * 2048 + n] = acc[i][j][r];
      }
    }
}

extern "C" void kernel_launch(void* const* d_in, const int* in_sizes, int n_in,
                              void* d_out, int out_size, void* d_ws, size_t ws_size,
                              hipStream_t stream) {
  (void)in_sizes; (void)n_in; (void)out_size; (void)ws_size;
  const float* x = (const float*)d_in[0];
  const float* Wq = (const float*)d_in[1];
  const float* Wk = (const float*)d_in[2];
  const float* Wv = (const float*)d_in[3];
  const float* Wout = (const float*)d_in[4];
  const float* ascale = (const float*)d_in[5];

  char* ws = (char*)d_ws;
  f16* x16 = (f16*)(ws);                       // 16 MB
  f16* WoutT = (f16*)(ws + (16ull << 20));     // 8 MB
  f16* WqT = (f16*)(ws + (24ull << 20));       // 8 MB
  f16* WkT = (f16*)(ws + (32ull << 20));       // 8 MB
  f16* WvT = (f16*)(ws + (40ull << 20));       // 8 MB
  f16* qh = (f16*)(ws + (48ull << 20));        // 16 MB  (B,H,L,Dh)
  f16* kh = (f16*)(ws + (64ull << 20));        // 16 MB
  f16* vT = (f16*)(ws + (80ull << 20));        // 16 MB  (B,H,Dh,L)
  f16* attO = (f16*)(ws + (24ull << 20));      // 16 MB, aliases WqT/WkT (dead by then)

  // 1) cast x to fp16
  k_cast<<<dim3(4096), dim3(256), 0, stream>>>(x, x16, 1048576);
  // 2) transpose + cast the 4 weight matrices to (N,K) fp16
  k_transpose4<<<dim3(64, 64, 4), dim3(32, 8), 0, stream>>>(Wq, Wk, Wv, Wout,
                                                            WqT, WkT, WvT, WoutT);
  // 3) QKV projection
  k_gemm_qkv<<<dim3(16, 32, 3), dim3(256), 0, stream>>>(x16, WqT, WkT, WvT, qh, kh, vT);
  // 4) RoPE + normalize q,k in place
  k_rope_norm<<<dim3(32768), dim3(256), 0, stream>>>(qh, kh);
  // 5) causal flash attention
  k_flash<<<dim3(16, 32), dim3(256), 0, stream>>>(qh, kh, vT, attO, ascale);
  // 6) output projection
  k_gemm_out<<<dim3(16, 32), dim3(256), 0, stream>>>(attO, WoutT, (float*)d_out);
}

// Round 2
// 441.551 us; speedup vs baseline: 1.3234x; 1.3234x over previous
//
#include <hip/hip_runtime.h>
#include <hip/hip_fp16.h>

#define B_ 2
#define L_ 2048
#define D_ 2048
#define H_ 16
#define DH_ 128

typedef _Float16 f16;
typedef _Float16 f16x8 __attribute__((ext_vector_type(8)));
typedef _Float16 f16x4 __attribute__((ext_vector_type(4)));
typedef _Float16 f16x2 __attribute__((ext_vector_type(2)));
typedef float f32x4 __attribute__((ext_vector_type(4)));

__device__ __forceinline__ void gload_lds16(const void* g, void* l) {
  __builtin_amdgcn_global_load_lds(
      (__attribute__((address_space(1))) void*)(void*)g,
      (__attribute__((address_space(3))) void*)l, 16, 0, 0);
}

__device__ __forceinline__ float rmax16(float v) {
  v = fmaxf(v, __shfl_xor(v, 1));
  v = fmaxf(v, __shfl_xor(v, 2));
  v = fmaxf(v, __shfl_xor(v, 4));
  v = fmaxf(v, __shfl_xor(v, 8));
  return v;
}
__device__ __forceinline__ float rsum16(float v) {
  v += __shfl_xor(v, 1);
  v += __shfl_xor(v, 2);
  v += __shfl_xor(v, 4);
  v += __shfl_xor(v, 8);
  return v;
}

// ---------------- kernel 1: cast x fp32 -> fp16 ----------------
__global__ __launch_bounds__(256) void k_cast(const float* __restrict__ in,
                                              f16* __restrict__ out, int n8) {
  int i = blockIdx.x * blockDim.x + threadIdx.x;
  if (i >= n8) return;
  const float4* p = (const float4*)in + (size_t)i * 2;
  float4 a = p[0], b = p[1];
  f16x8 o;
  o[0] = (f16)a.x; o[1] = (f16)a.y; o[2] = (f16)a.z; o[3] = (f16)a.w;
  o[4] = (f16)b.x; o[5] = (f16)b.y; o[6] = (f16)b.z; o[7] = (f16)b.w;
  *((f16x8*)out + i) = o;
}

// ------- kernel 2: transpose+cast 2048x2048 fp32 -> fp16 (N x K) -------
__global__ __launch_bounds__(256) void k_transpose4(
    const float* __restrict__ W0, const float* __restrict__ W1,
    const float* __restrict__ W2, const float* __restrict__ W3,
    f16* __restrict__ T0, f16* __restrict__ T1, f16* __restrict__ T2,
    f16* __restrict__ T3) {
  int z = blockIdx.z;
  const float* src = (z == 0) ? W0 : (z == 1) ? W1 : (z == 2) ? W2 : W3;
  f16* dst = (z == 0) ? T0 : (z == 1) ? T1 : (z == 2) ? T2 : T3;
  __shared__ float tile[32][33];
  int tx = threadIdx.x, ty = threadIdx.y;
  int x = blockIdx.x * 32 + tx;
  int y0 = blockIdx.y * 32;
#pragma unroll
  for (int i = 0; i < 4; ++i)
    tile[ty + i * 8][tx] = src[(size_t)(y0 + ty + i * 8) * 2048 + x];
  __syncthreads();
  int ox = y0 + tx;               // k index in output
  int oy0 = blockIdx.x * 32;      // n base
#pragma unroll
  for (int i = 0; i < 4; ++i)
    dst[(size_t)(oy0 + ty + i * 8) * 2048 + ox] = (f16)tile[tx][ty + i * 8];
}

// ---------------- shared GEMM core: 128x128 tile, BK=32 ----------------
// A: M x K fp16 row-major.  BT: N x K fp16 row-major.  K = 2048.
__device__ __forceinline__ void gemm_core(const f16* __restrict__ A,
                                          const f16* __restrict__ BT,
                                          f16* As, f16* Bs, int m0, int n0,
                                          f32x4 (&acc)[4][4]) {
  const int tid = threadIdx.x;
  const int lane = tid & 63, w = tid >> 6;
  const int wr = w >> 1, wc = w & 1;
  const int li = lane & 15, lg = lane >> 4;
  for (int kt = 0; kt < 64; ++kt) {
    __syncthreads();
#pragma unroll
    for (int p = 0; p < 2; ++p) {
      int o = tid * 16 + p * 4096;      // byte offset into 8KB tile
      int row = o >> 6, cb = o & 63;    // 64B per row (32 halfs)
      gload_lds16((const char*)A + (size_t)(m0 + row) * 4096 + kt * 64 + cb,
                  (char*)As + o);
      gload_lds16((const char*)BT + (size_t)(n0 + row) * 4096 + kt * 64 + cb,
                  (char*)Bs + o);
    }
    __syncthreads();
    f16x8 af[4], bf[4];
#pragma unroll
    for (int i = 0; i < 4; ++i) {
      af[i] = *(const f16x8*)(As + (wr * 64 + i * 16 + li) * 32 + lg * 8);
      bf[i] = *(const f16x8*)(Bs + (wc * 64 + i * 16 + li) * 32 + lg * 8);
    }
#pragma unroll
    for (int i = 0; i < 4; ++i)
#pragma unroll
      for (int j = 0; j < 4; ++j)
        acc[i][j] =
            __builtin_amdgcn_mfma_f32_16x16x32_f16(af[i], bf[j], acc[i][j], 0, 0, 0);
  }
}

// --------- kernel 3: QKV projection, epilogues write q/k head-major, v transposed ---------
__global__ __launch_bounds__(256) void k_gemm_qkv(
    const f16* __restrict__ x16, const f16* __restrict__ WqT,
    const f16* __restrict__ WkT, const f16* __restrict__ WvT,
    f16* __restrict__ qh, f16* __restrict__ kh, f16* __restrict__ vTo) {
  __shared__ alignas(16) f16 As[128 * 32];
  __shared__ alignas(16) f16 Bs[128 * 32];
  const int z = blockIdx.z;
  const f16* BT = (z == 0) ? WqT : (z == 1) ? WkT : WvT;
  const int m0 = blockIdx.y * 128, n0 = blockIdx.x * 128;
  f32x4 acc[4][4] = {};
  gemm_core(x16, BT, As, Bs, m0, n0, acc);
  const int lane = threadIdx.x & 63, w = threadIdx.x >> 6;
  const int wr = w >> 1, wc = w & 1, li = lane & 15, lg = lane >> 4;
  if (z < 2) {
    f16* out = (z == 0) ? qh : kh;
#pragma unroll
    for (int i = 0; i < 4; ++i) {
      int mb = m0 + wr * 64 + i * 16 + lg * 4;
#pragma unroll
      for (int j = 0; j < 4; ++j) {
        int n = n0 + wc * 64 + j * 16 + li;
        int h = n >> 7, dh = n & 127;
#pragma unroll
        for (int r = 0; r < 4; ++r) {
          int m = mb + r;
          int b = m >> 11, l = m & 2047;
          out[(((size_t)(b * 16 + h) * 2048 + l) << 7) + dh] = (f16)acc[i][j][r];
        }
      }
    }
  } else {
#pragma unroll
    for (int i = 0; i < 4; ++i) {
      int mb = m0 + wr * 64 + i * 16 + lg * 4;  // multiple of 4
      int b = mb >> 11, l = mb & 2047;
#pragma unroll
      for (int j = 0; j < 4; ++j) {
        int n = n0 + wc * 64 + j * 16 + li;
        int h = n >> 7, dh = n & 127;
        f16x4 v4;
#pragma unroll
        for (int r = 0; r < 4; ++r) v4[r] = (f16)acc[i][j][r];
        *(f16x4*)(vTo + ((size_t)(b * 16 + h) * 128 + dh) * 2048 + l) = v4;
      }
    }
  }
}

// ---------------- kernel 4: RoPE + L2 normalize, in place on qh/kh ----------------
__global__ __launch_bounds__(256) void k_rope_norm(f16* __restrict__ qh,
                                                   f16* __restrict__ kh) {
  int gid = blockIdx.x * 4 + (threadIdx.x >> 6);  // 0 .. 131071
  int lane = threadIdx.x & 63;
  int which = gid >> 16;
  int r = gid & 65535;          // (b*16+h)*2048 + l
  int l = r & 2047;
  f16* base = (which ? kh : qh) + (size_t)r * 128;
  f16x2 xv = *(f16x2*)(base + lane * 2);
  float x0 = (float)xv[0], x1 = (float)xv[1];
  float invf = exp2f(-(float)lane * 0.29580575889569f);
  float ang = (float)l * invf;
  float s, c;
  sincosf(ang, &s, &c);
  float y0 = x0 * c - x1 * s;
  float y1 = x1 * c + x0 * s;
  float ss = y0 * y0 + y1 * y1;
  ss += __shfl_xor(ss, 1);  ss += __shfl_xor(ss, 2);
  ss += __shfl_xor(ss, 4);  ss += __shfl_xor(ss, 8);
  ss += __shfl_xor(ss, 16); ss += __shfl_xor(ss, 32);
  float inv = 1.0f / (sqrtf(ss) + 1e-6f);
  f16x2 o;
  o[0] = (f16)(y0 * inv);
  o[1] = (f16)(y1 * inv);
  *(f16x2*)(base + lane * 2) = o;
}

// ---------------- kernel 5: flash attention (causal), load-balanced ----------------
// 32 q-tiles of 64 rows; block (pair,bh) handles q-tiles {pair, 31-pair} -> uniform
// 33 k-tiles per block. 4 waves x 16 q-rows. grid = (16, 32).
__global__ __launch_bounds__(256) void k_flash(
    const f16* __restrict__ qh, const f16* __restrict__ kh,
    const f16* __restrict__ vT, f16* __restrict__ attO,
    const float* __restrict__ ascale_p) {
  const int bh = blockIdx.y;
  const int tid = threadIdx.x, lane = tid & 63, w = tid >> 6;
  const int li = lane & 15, lg = lane >> 4;
  const float csc = ascale_p[0] * 1.44269504088896f;  // attn_scale * log2(e)
  const float thr = 8.0f / csc;                       // defer-max threshold (raw)

  __shared__ alignas(16) f16 Ks[64 * 136];
  __shared__ alignas(16) f16 Vs[128 * 72];
  __shared__ alignas(16) f16 Ps[4][16 * 72];

  const f16* qb = qh + (size_t)bh * 2048 * 128;
  const f16* kb = kh + (size_t)bh * 2048 * 128;
  const f16* vb = vT + (size_t)bh * 128 * 2048;
  const int b = bh >> 4, h = bh & 15;

#pragma unroll 1
  for (int ti = 0; ti < 2; ++ti) {
    const int t = ti ? (31 - (int)blockIdx.x) : (int)blockIdx.x;
    const int qw = t * 64 + w * 16;

    f16x8 Qr[4];
#pragma unroll
    for (int ks = 0; ks < 4; ++ks)
      Qr[ks] = *(const f16x8*)(qb + (size_t)(qw + li) * 128 + ks * 32 + lg * 8);

    f32x4 Oa[8] = {};
    float mrow[4], lrow[4];
#pragma unroll
    for (int r = 0; r < 4; ++r) { mrow[r] = -1e30f; lrow[r] = 0.0f; }

#pragma unroll 1
    for (int kt = 0; kt <= t; ++kt) {
      const int k0 = kt * 64;
      __syncthreads();
#pragma unroll
      for (int p = 0; p < 4; ++p) {
        int e = (p * 256 + tid) * 8;
        int row = e >> 7, col = e & 127;
        *(f16x8*)(Ks + row * 136 + col) =
            *(const f16x8*)(kb + (size_t)(k0 + row) * 128 + col);
        int row2 = e >> 6, col2 = e & 63;
        *(f16x8*)(Vs + row2 * 72 + col2) =
            *(const f16x8*)(vb + (size_t)row2 * 2048 + k0 + col2);
      }
      __syncthreads();

      // S = Q K^T   (16 q-rows x 64 k-cols per wave)
      f32x4 Sa[4] = {};
      __builtin_amdgcn_s_setprio(1);
#pragma unroll
      for (int ks = 0; ks < 4; ++ks) {
        f16x8 kf4[4];
#pragma unroll
        for (int kf = 0; kf < 4; ++kf)
          kf4[kf] = *(const f16x8*)(Ks + (kf * 16 + li) * 136 + ks * 32 + lg * 8);
#pragma unroll
        for (int kf = 0; kf < 4; ++kf)
          Sa[kf] = __builtin_amdgcn_mfma_f32_16x16x32_f16(Qr[ks], kf4[kf],
                                                          Sa[kf], 0, 0, 0);
      }
      __builtin_amdgcn_s_setprio(0);

      if (kt == t) {  // diagonal tile: causal mask
#pragma unroll
        for (int kf = 0; kf < 4; ++kf)
#pragma unroll
          for (int r = 0; r < 4; ++r) {
            int qq = qw + lg * 4 + r;
            int kk = k0 + kf * 16 + li;
            if (kk > qq) Sa[kf][r] = -1e30f;
          }
      }

      // online softmax with defer-max
      float vmax[4];
      bool need = false;
#pragma unroll
      for (int r = 0; r < 4; ++r) {
        float v = fmaxf(fmaxf(Sa[0][r], Sa[1][r]), fmaxf(Sa[2][r], Sa[3][r]));
        v = rmax16(v);
        vmax[r] = v;
        need |= (v > mrow[r] + thr);
      }
      if (__any(need)) {
#pragma unroll
        for (int r = 0; r < 4; ++r) {
          float mnew = fmaxf(mrow[r], vmax[r]);
          float sc = exp2f(csc * (mrow[r] - mnew));
          mrow[r] = mnew;
          lrow[r] *= sc;
#pragma unroll
          for (int df = 0; df < 8; ++df) Oa[df][r] *= sc;
        }
      }
#pragma unroll
      for (int r = 0; r < 4; ++r) {
        float rs = 0.0f;
#pragma unroll
        for (int kf = 0; kf < 4; ++kf) {
          float p = exp2f(csc * (Sa[kf][r] - mrow[r]));
          Sa[kf][r] = p;
          rs += p;
        }
        rs = rsum16(rs);
        lrow[r] += rs;
      }

      // P -> LDS (per-wave buffer), then PV
      f16* Pw = &Ps[w][0];
#pragma unroll
      for (int kf = 0; kf < 4; ++kf)
#pragma unroll
        for (int r = 0; r < 4; ++r)
          Pw[(lg * 4 + r) * 72 + kf * 16 + li] = (f16)Sa[kf][r];
      asm volatile("s_waitcnt lgkmcnt(0)" ::: "memory");
      __builtin_amdgcn_sched_barrier(0);
      __builtin_amdgcn_s_setprio(1);
#pragma unroll
      for (int k2 = 0; k2 < 2; ++k2) {
        f16x8 pa, vfr[8];
        pa = *(const f16x8*)(Pw + li * 72 + k2 * 32 + lg * 8);
#pragma unroll
        for (int df = 0; df < 8; ++df)
          vfr[df] = *(const f16x8*)(Vs + (df * 16 + li) * 72 + k2 * 32 + lg * 8);
#pragma unroll
        for (int df = 0; df < 8; ++df)
          Oa[df] = __builtin_amdgcn_mfma_f32_16x16x32_f16(pa, vfr[df],
                                                          Oa[df], 0, 0, 0);
      }
      __builtin_amdgcn_s_setprio(0);
    }

    // epilogue: O /= l, write (B,L,H*Dh) fp16
#pragma unroll
    for (int r = 0; r < 4; ++r) {
      float inv = 1.0f / lrow[r];
      int q = qw + lg * 4 + r;
      f16* orow = attO + (size_t)(b * 2048 + q) * 2048 + h * 128;
#pragma unroll
      for (int df = 0; df < 8; ++df)
        orow[df * 16 + li] = (f16)(Oa[df][r] * inv);
    }
  }
}

// ---------------- kernel 6: output projection -> fp32 ----------------
__global__ __launch_bounds__(256) void k_gemm_out(const f16* __restrict__ A,
                                                  const f16* __restrict__ WoutT,
                                                  float* __restrict__ out) {
  __shared__ alignas(16) f16 As[128 * 32];
  __shared__ alignas(16) f16 Bs[128 * 32];
  const int m0 = blockIdx.y * 128, n0 = blockIdx.x * 128;
  f32x4 acc[4][4] = {};
  gemm_core(A, WoutT, As, Bs, m0, n0, acc);
  const int lane = threadIdx.x & 63, w = threadIdx.x >> 6;
  const int wr = w >> 1, wc = w & 1, li = lane & 15, lg = lane >> 4;
#pragma unroll
  for (int i = 0; i < 4; ++i)
#pragma unroll
    for (int j = 0; j < 4; ++j) {
      int n = n0 + wc * 64 + j * 16 + li;
#pragma unroll
      for (int r = 0; r < 4; ++r) {
        int m = m0 + wr * 64 + i * 16 + lg * 4 + r;
        out[(size_t)m * 2048 + n] = acc[i][j][r];
      }
    }
}

extern "C" void kernel_launch(void* const* d_in, const int* in_sizes, int n_in,
                              void* d_out, int out_size, void* d_ws, size_t ws_size,
                              hipStream_t stream) {
  (void)in_sizes; (void)n_in; (void)out_size; (void)ws_size;
  const float* x = (const float*)d_in[0];
  const float* Wq = (const float*)d_in[1];
  const float* Wk = (const float*)d_in[2];
  const float* Wv = (const float*)d_in[3];
  const float* Wout = (const float*)d_in[4];
  const float* ascale = (const float*)d_in[5];

  char* ws = (char*)d_ws;
  f16* x16 = (f16*)(ws);                       // 16 MB
  f16* WoutT = (f16*)(ws + (16ull << 20));     // 8 MB
  f16* WqT = (f16*)(ws + (24ull << 20));       // 8 MB
  f16* WkT = (f16*)(ws + (32ull << 20));       // 8 MB
  f16* WvT = (f16*)(ws + (40ull << 20));       // 8 MB
  f16* qh = (f16*)(ws + (48ull << 20));        // 16 MB  (B,H,L,Dh)
  f16* kh = (f16*)(ws + (64ull << 20));        // 16 MB
  f16* vT = (f16*)(ws + (80ull << 20));        // 16 MB  (B,H,Dh,L)
  f16* attO = (f16*)(ws + (24ull << 20));      // 16 MB, aliases WqT/WkT (dead by then)

  k_cast<<<dim3(4096), dim3(256), 0, stream>>>(x, x16, 1048576);
  k_transpose4<<<dim3(64, 64, 4), dim3(32, 8), 0, stream>>>(Wq, Wk, Wv, Wout,
                                                            WqT, WkT, WvT, WoutT);
  k_gemm_qkv<<<dim3(16, 32, 3), dim3(256), 0, stream>>>(x16, WqT, WkT, WvT, qh, kh, vT);
  k_rope_norm<<<dim3(32768), dim3(256), 0, stream>>>(qh, kh);
  k_flash<<<dim3(16, 32), dim3(256), 0, stream>>>(qh, kh, vT, attO, ascale);
  k_gemm_out<<<dim3(16, 32), dim3(256), 0, stream>>>(attO, WoutT, (float*)d_out);
}

// Round 3
// 435.602 us; speedup vs baseline: 1.3415x; 1.0137x over previous
//
#include <hip/hip_runtime.h>
#include <hip/hip_fp16.h>

#define B_ 2
#define L_ 2048
#define D_ 2048
#define H_ 16
#define DH_ 128

typedef _Float16 f16;
typedef _Float16 f16x8 __attribute__((ext_vector_type(8)));
typedef _Float16 f16x4 __attribute__((ext_vector_type(4)));
typedef _Float16 f16x2 __attribute__((ext_vector_type(2)));
typedef float f32x4 __attribute__((ext_vector_type(4)));

__device__ __forceinline__ void gload_lds16(const void* g, void* l) {
  __builtin_amdgcn_global_load_lds(
      (__attribute__((address_space(1))) void*)(void*)g,
      (__attribute__((address_space(3))) void*)l, 16, 0, 0);
}

template <int N>
__device__ __forceinline__ void waitcnt_vm() {
  if constexpr (N == 0) asm volatile("s_waitcnt vmcnt(0)" ::: "memory");
  else if constexpr (N == 4) asm volatile("s_waitcnt vmcnt(4)" ::: "memory");
  else if constexpr (N == 6) asm volatile("s_waitcnt vmcnt(6)" ::: "memory");
  else if constexpr (N == 8) asm volatile("s_waitcnt vmcnt(8)" ::: "memory");
}

__device__ __forceinline__ float rmax16(float v) {
  v = fmaxf(v, __shfl_xor(v, 1));
  v = fmaxf(v, __shfl_xor(v, 2));
  v = fmaxf(v, __shfl_xor(v, 4));
  v = fmaxf(v, __shfl_xor(v, 8));
  return v;
}
__device__ __forceinline__ float rsum16(float v) {
  v += __shfl_xor(v, 1);
  v += __shfl_xor(v, 2);
  v += __shfl_xor(v, 4);
  v += __shfl_xor(v, 8);
  return v;
}

// ---------------- kernel 1: cast x fp32 -> fp16 ----------------
__global__ __launch_bounds__(256) void k_cast(const float* __restrict__ in,
                                              f16* __restrict__ out, int n8) {
  int i = blockIdx.x * blockDim.x + threadIdx.x;
  if (i >= n8) return;
  const float4* p = (const float4*)in + (size_t)i * 2;
  float4 a = p[0], b = p[1];
  f16x8 o;
  o[0] = (f16)a.x; o[1] = (f16)a.y; o[2] = (f16)a.z; o[3] = (f16)a.w;
  o[4] = (f16)b.x; o[5] = (f16)b.y; o[6] = (f16)b.z; o[7] = (f16)b.w;
  *((f16x8*)out + i) = o;
}

// ------- kernel 2: transpose+cast 2048x2048 fp32 -> fp16 (N x K) -------
__global__ __launch_bounds__(256) void k_transpose4(
    const float* __restrict__ W0, const float* __restrict__ W1,
    const float* __restrict__ W2, const float* __restrict__ W3,
    f16* __restrict__ T0, f16* __restrict__ T1, f16* __restrict__ T2,
    f16* __restrict__ T3) {
  int z = blockIdx.z;
  const float* src = (z == 0) ? W0 : (z == 1) ? W1 : (z == 2) ? W2 : W3;
  f16* dst = (z == 0) ? T0 : (z == 1) ? T1 : (z == 2) ? T2 : T3;
  __shared__ float tile[32][33];
  int tx = threadIdx.x, ty = threadIdx.y;
  int x = blockIdx.x * 32 + tx;
  int y0 = blockIdx.y * 32;
#pragma unroll
  for (int i = 0; i < 4; ++i)
    tile[ty + i * 8][tx] = src[(size_t)(y0 + ty + i * 8) * 2048 + x];
  __syncthreads();
  int ox = y0 + tx;
  int oy0 = blockIdx.x * 32;
#pragma unroll
  for (int i = 0; i < 4; ++i)
    dst[(size_t)(oy0 + ty + i * 8) * 2048 + ox] = (f16)tile[tx][ty + i * 8];
}

// ======== 8-phase GEMM core (T2+T3+T4+T5), BN=256, BK=64, 8 waves ========
// A: M x 2048 f16 row-major (4096 B/row). BT: N x 2048 f16 row-major.
// LDS per buffer: A tile [BM][64] halfs + B tile [256][64] halfs,
// 16B-chunk XOR swizzle: chunk ^= (row & 7)  (both-sides: swizzled global
// source on stage, swizzled address on ds_read; gload_lds dest stays linear).

template <int NL>
__device__ __forceinline__ void stage_slot(const char* __restrict__ src,
                                           char* dst, int tid) {
#pragma unroll
  for (int j = 0; j < NL; ++j) {
    int ci = j * 512 + tid;
    int row = ci >> 3;
    int sc = (ci & 7) ^ (row & 7);
    gload_lds16(src + (size_t)row * 4096 + sc * 16, dst + ci * 16);
  }
}

template <int BM>
__device__ __forceinline__ void gemm8_core(const f16* __restrict__ A,
                                           const f16* __restrict__ BT,
                                           char* lds, int m0, int n0,
                                           f32x4 (&acc)[BM / 32][4]) {
  constexpr int WRS = BM / 2;           // rows per wr-half
  constexpr int MR = BM / 32;           // m-frags per wave
  constexpr int MPP = MR / 4;           // m-frags per phase
  constexpr int ALOADS = BM / 128;      // loads/thread per A half-slot
  constexpr int LPT = 2 * ALOADS + 4;   // loads/thread per K-tile
  constexpr int ABYTES = BM * 128;
  constexpr int BUFB = ABYTES + 32768;
  constexpr int nt = 32;                // K / 64

  const int tid = threadIdx.x;
  const int lane = tid & 63, w = tid >> 6;
  const int wr = w >> 2, wc = w & 3;
  const int li = lane & 15, lg = lane >> 4;

  const char* Ab = (const char*)A + (size_t)m0 * 4096;
  const char* Bb = (const char*)BT + (size_t)n0 * 4096;

  // swizzled per-thread read offsets (bytes)
  const int aoff0 = (wr * WRS + li) * 128 + ((lg) ^ (li & 7)) * 16;
  const int aoff1 = (wr * WRS + li) * 128 + ((4 + lg) ^ (li & 7)) * 16;
  const int boff0 = (wc * 64 + li) * 128 + ((lg) ^ (li & 7)) * 16;
  const int boff1 = (wc * 64 + li) * 128 + ((4 + lg) ^ (li & 7)) * 16;

  // prologue: stage tiles 0 -> buf0, 1 -> buf1
#pragma unroll
  for (int t = 0; t < 2; ++t) {
    char* bA = lds + t * BUFB;
    stage_slot<ALOADS>(Ab + t * 128, bA, tid);
    stage_slot<ALOADS>(Ab + (size_t)WRS * 4096 + t * 128, bA + (size_t)WRS * 128, tid);
    stage_slot<2>(Bb + t * 128, bA + ABYTES, tid);
    stage_slot<2>(Bb + (size_t)128 * 4096 + t * 128, bA + ABYTES + 128 * 128, tid);
  }
  waitcnt_vm<LPT>();   // tile 0 landed; tile 1 still in flight
  __builtin_amdgcn_s_barrier();

#pragma unroll 1
  for (int u = 0; u < nt; ++u) {
    const int c = u & 1;
    char* bufA = lds + c * BUFB;
    char* bufB = bufA + ABYTES;
    char* oA = lds + (c ^ 1) * BUFB;   // other buffer's A region
    f16x8 bf[4][2];
#pragma unroll
    for (int p = 0; p < 4; ++p) {
      // --- ds-load register subtile ---
      f16x8 af[MPP][2];
#pragma unroll
      for (int i = 0; i < MPP; ++i) {
        af[i][0] = *(const f16x8*)(bufA + aoff0 + (p * MPP + i) * 2048);
        af[i][1] = *(const f16x8*)(bufA + aoff1 + (p * MPP + i) * 2048);
      }
      if (p == 0) {
#pragma unroll
        for (int nc = 0; nc < 4; ++nc) {
          bf[nc][0] = *(const f16x8*)(bufB + boff0 + nc * 2048);
          bf[nc][1] = *(const f16x8*)(bufB + boff1 + nc * 2048);
        }
      }
      // --- stage one half-tile (buffer-safe pattern) ---
      if (p == 0 && u >= 1 && u + 1 < nt)
        stage_slot<ALOADS>(Ab + (size_t)(u + 1) * 128, oA, tid);
      if (p == 1 && u >= 1 && u + 1 < nt)
        stage_slot<ALOADS>(Ab + (size_t)WRS * 4096 + (size_t)(u + 1) * 128,
                           oA + (size_t)WRS * 128, tid);
      if (p == 2 && u + 2 < nt)
        stage_slot<2>(Bb + (size_t)(u + 2) * 128, bufB, tid);
      if (p == 3 && u + 2 < nt)
        stage_slot<2>(Bb + (size_t)128 * 4096 + (size_t)(u + 2) * 128,
                      bufB + 128 * 128, tid);
      if (p == 3) {
        if (u + 2 < nt) waitcnt_vm<4>();        // keep next B-halves in flight
        else if (u + 1 < nt) waitcnt_vm<0>();   // drain tail
      }
      __builtin_amdgcn_s_barrier();
      asm volatile("s_waitcnt lgkmcnt(0)" ::: "memory");
      __builtin_amdgcn_sched_barrier(0);
      __builtin_amdgcn_s_setprio(1);
#pragma unroll
      for (int i = 0; i < MPP; ++i)
#pragma unroll
        for (int nc = 0; nc < 4; ++nc) {
          acc[p * MPP + i][nc] = __builtin_amdgcn_mfma_f32_16x16x32_f16(
              af[i][0], bf[nc][0], acc[p * MPP + i][nc], 0, 0, 0);
          acc[p * MPP + i][nc] = __builtin_amdgcn_mfma_f32_16x16x32_f16(
              af[i][1], bf[nc][1], acc[p * MPP + i][nc], 0, 0, 0);
        }
      __builtin_amdgcn_s_setprio(0);
      __builtin_amdgcn_s_barrier();
    }
  }
}

// --------- kernel 3: QKV projection (BM=256), fused z, XCD swizzle ---------
__global__ __launch_bounds__(512, 2) void k_gemm8_qkv(
    const f16* __restrict__ x16, const f16* __restrict__ WqT,
    const f16* __restrict__ WkT, const f16* __restrict__ WvT,
    f16* __restrict__ qh, f16* __restrict__ kh, f16* __restrict__ vTo) {
  __shared__ alignas(16) char lds[2 * (256 * 128 + 32768)];  // 128 KiB
  const int pb = blockIdx.x;                 // 0..383, 384 % 8 == 0
  const int lgc = (pb & 7) * 48 + (pb >> 3); // bijective XCD chunking
  const int z = lgc >> 7;
  const int r = lgc & 127;
  const int m0 = (r >> 3) * 256, n0 = (r & 7) * 256;
  const f16* BT = (z == 0) ? WqT : (z == 1) ? WkT : WvT;
  f32x4 acc[8][4] = {};
  gemm8_core<256>(x16, BT, lds, m0, n0, acc);

  const int lane = threadIdx.x & 63, w = threadIdx.x >> 6;
  const int wr = w >> 2, wc = w & 3, li = lane & 15, lg = lane >> 4;
  if (z < 2) {
    f16* out = (z == 0) ? qh : kh;
#pragma unroll
    for (int mr = 0; mr < 8; ++mr) {
      int mb = m0 + wr * 128 + mr * 16 + lg * 4;
#pragma unroll
      for (int nc = 0; nc < 4; ++nc) {
        int n = n0 + wc * 64 + nc * 16 + li;
        int h = n >> 7, dh = n & 127;
#pragma unroll
        for (int r2 = 0; r2 < 4; ++r2) {
          int m = mb + r2;
          int b = m >> 11, l = m & 2047;
          out[(((size_t)(b * 16 + h) * 2048 + l) << 7) + dh] = (f16)acc[mr][nc][r2];
        }
      }
    }
  } else {
#pragma unroll
    for (int mr = 0; mr < 8; ++mr) {
      int mb = m0 + wr * 128 + mr * 16 + lg * 4;  // multiple of 4
      int b = mb >> 11, l = mb & 2047;
#pragma unroll
      for (int nc = 0; nc < 4; ++nc) {
        int n = n0 + wc * 64 + nc * 16 + li;
        int h = n >> 7, dh = n & 127;
        f16x4 v4;
#pragma unroll
        for (int r2 = 0; r2 < 4; ++r2) v4[r2] = (f16)acc[mr][nc][r2];
        *(f16x4*)(vTo + ((size_t)(b * 16 + h) * 128 + dh) * 2048 + l) = v4;
      }
    }
  }
}

// --------- kernel 6: output projection (BM=128 -> 256 blocks, balanced) ---------
__global__ __launch_bounds__(512, 2) void k_gemm8_out(
    const f16* __restrict__ A, const f16* __restrict__ WoutT,
    float* __restrict__ out) {
  __shared__ alignas(16) char lds[2 * (128 * 128 + 32768)];  // 96 KiB
  const int pb = blockIdx.x;                 // 0..255
  const int lgc = (pb & 7) * 32 + (pb >> 3);
  const int m0 = (lgc >> 3) * 128, n0 = (lgc & 7) * 256;
  f32x4 acc[4][4] = {};
  gemm8_core<128>(A, WoutT, lds, m0, n0, acc);

  const int lane = threadIdx.x & 63, w = threadIdx.x >> 6;
  const int wr = w >> 2, wc = w & 3, li = lane & 15, lg = lane >> 4;
#pragma unroll
  for (int mr = 0; mr < 4; ++mr) {
#pragma unroll
    for (int nc = 0; nc < 4; ++nc) {
      int n = n0 + wc * 64 + nc * 16 + li;
#pragma unroll
      for (int r2 = 0; r2 < 4; ++r2) {
        int m = m0 + wr * 64 + mr * 16 + lg * 4 + r2;
        out[(size_t)m * 2048 + n] = acc[mr][nc][r2];
      }
    }
  }
}

// ---------------- kernel 4: RoPE + L2 normalize, in place on qh/kh ----------------
__global__ __launch_bounds__(256) void k_rope_norm(f16* __restrict__ qh,
                                                   f16* __restrict__ kh) {
  int gid = blockIdx.x * 4 + (threadIdx.x >> 6);
  int lane = threadIdx.x & 63;
  int which = gid >> 16;
  int r = gid & 65535;
  int l = r & 2047;
  f16* base = (which ? kh : qh) + (size_t)r * 128;
  f16x2 xv = *(f16x2*)(base + lane * 2);
  float x0 = (float)xv[0], x1 = (float)xv[1];
  float invf = exp2f(-(float)lane * 0.29580575889569f);
  float ang = (float)l * invf;
  float s, c;
  sincosf(ang, &s, &c);
  float y0 = x0 * c - x1 * s;
  float y1 = x1 * c + x0 * s;
  float ss = y0 * y0 + y1 * y1;
  ss += __shfl_xor(ss, 1);  ss += __shfl_xor(ss, 2);
  ss += __shfl_xor(ss, 4);  ss += __shfl_xor(ss, 8);
  ss += __shfl_xor(ss, 16); ss += __shfl_xor(ss, 32);
  float inv = 1.0f / (sqrtf(ss) + 1e-6f);
  f16x2 o;
  o[0] = (f16)(y0 * inv);
  o[1] = (f16)(y1 * inv);
  *(f16x2*)(base + lane * 2) = o;
}

// ---------------- kernel 5: flash attention (causal), load-balanced ----------------
__global__ __launch_bounds__(256) void k_flash(
    const f16* __restrict__ qh, const f16* __restrict__ kh,
    const f16* __restrict__ vT, f16* __restrict__ attO,
    const float* __restrict__ ascale_p) {
  const int bh = blockIdx.y;
  const int tid = threadIdx.x, lane = tid & 63, w = tid >> 6;
  const int li = lane & 15, lg = lane >> 4;
  const float csc = ascale_p[0] * 1.44269504088896f;
  const float thr = 8.0f / csc;

  __shared__ alignas(16) f16 Ks[64 * 136];
  __shared__ alignas(16) f16 Vs[128 * 72];
  __shared__ alignas(16) f16 Ps[4][16 * 72];

  const f16* qb = qh + (size_t)bh * 2048 * 128;
  const f16* kb = kh + (size_t)bh * 2048 * 128;
  const f16* vb = vT + (size_t)bh * 128 * 2048;
  const int b = bh >> 4, h = bh & 15;

#pragma unroll 1
  for (int ti = 0; ti < 2; ++ti) {
    const int t = ti ? (31 - (int)blockIdx.x) : (int)blockIdx.x;
    const int qw = t * 64 + w * 16;

    f16x8 Qr[4];
#pragma unroll
    for (int ks = 0; ks < 4; ++ks)
      Qr[ks] = *(const f16x8*)(qb + (size_t)(qw + li) * 128 + ks * 32 + lg * 8);

    f32x4 Oa[8] = {};
    float mrow[4], lrow[4];
#pragma unroll
    for (int r = 0; r < 4; ++r) { mrow[r] = -1e30f; lrow[r] = 0.0f; }

#pragma unroll 1
    for (int kt = 0; kt <= t; ++kt) {
      const int k0 = kt * 64;
      __syncthreads();
#pragma unroll
      for (int p = 0; p < 4; ++p) {
        int e = (p * 256 + tid) * 8;
        int row = e >> 7, col = e & 127;
        *(f16x8*)(Ks + row * 136 + col) =
            *(const f16x8*)(kb + (size_t)(k0 + row) * 128 + col);
        int row2 = e >> 6, col2 = e & 63;
        *(f16x8*)(Vs + row2 * 72 + col2) =
            *(const f16x8*)(vb + (size_t)row2 * 2048 + k0 + col2);
      }
      __syncthreads();

      f32x4 Sa[4] = {};
      __builtin_amdgcn_s_setprio(1);
#pragma unroll
      for (int ks = 0; ks < 4; ++ks) {
        f16x8 kf4[4];
#pragma unroll
        for (int kf = 0; kf < 4; ++kf)
          kf4[kf] = *(const f16x8*)(Ks + (kf * 16 + li) * 136 + ks * 32 + lg * 8);
#pragma unroll
        for (int kf = 0; kf < 4; ++kf)
          Sa[kf] = __builtin_amdgcn_mfma_f32_16x16x32_f16(Qr[ks], kf4[kf],
                                                          Sa[kf], 0, 0, 0);
      }
      __builtin_amdgcn_s_setprio(0);

      if (kt == t) {
#pragma unroll
        for (int kf = 0; kf < 4; ++kf)
#pragma unroll
          for (int r = 0; r < 4; ++r) {
            int qq = qw + lg * 4 + r;
            int kk = k0 + kf * 16 + li;
            if (kk > qq) Sa[kf][r] = -1e30f;
          }
      }

      float vmax[4];
      bool need = false;
#pragma unroll
      for (int r = 0; r < 4; ++r) {
        float v = fmaxf(fmaxf(Sa[0][r], Sa[1][r]), fmaxf(Sa[2][r], Sa[3][r]));
        v = rmax16(v);
        vmax[r] = v;
        need |= (v > mrow[r] + thr);
      }
      if (__any(need)) {
#pragma unroll
        for (int r = 0; r < 4; ++r) {
          float mnew = fmaxf(mrow[r], vmax[r]);
          float sc = exp2f(csc * (mrow[r] - mnew));
          mrow[r] = mnew;
          lrow[r] *= sc;
#pragma unroll
          for (int df = 0; df < 8; ++df) Oa[df][r] *= sc;
        }
      }
#pragma unroll
      for (int r = 0; r < 4; ++r) {
        float rs = 0.0f;
#pragma unroll
        for (int kf = 0; kf < 4; ++kf) {
          float p = exp2f(csc * (Sa[kf][r] - mrow[r]));
          Sa[kf][r] = p;
          rs += p;
        }
        rs = rsum16(rs);
        lrow[r] += rs;
      }

      f16* Pw = &Ps[w][0];
#pragma unroll
      for (int kf = 0; kf < 4; ++kf)
#pragma unroll
        for (int r = 0; r < 4; ++r)
          Pw[(lg * 4 + r) * 72 + kf * 16 + li] = (f16)Sa[kf][r];
      asm volatile("s_waitcnt lgkmcnt(0)" ::: "memory");
      __builtin_amdgcn_sched_barrier(0);
      __builtin_amdgcn_s_setprio(1);
#pragma unroll
      for (int k2 = 0; k2 < 2; ++k2) {
        f16x8 pa, vfr[8];
        pa = *(const f16x8*)(Pw + li * 72 + k2 * 32 + lg * 8);
#pragma unroll
        for (int df = 0; df < 8; ++df)
          vfr[df] = *(const f16x8*)(Vs + (df * 16 + li) * 72 + k2 * 32 + lg * 8);
#pragma unroll
        for (int df = 0; df < 8; ++df)
          Oa[df] = __builtin_amdgcn_mfma_f32_16x16x32_f16(pa, vfr[df],
                                                          Oa[df], 0, 0, 0);
      }
      __builtin_amdgcn_s_setprio(0);
    }

#pragma unroll
    for (int r = 0; r < 4; ++r) {
      float inv = 1.0f / lrow[r];
      int q = qw + lg * 4 + r;
      f16* orow = attO + (size_t)(b * 2048 + q) * 2048 + h * 128;
#pragma unroll
      for (int df = 0; df < 8; ++df)
        orow[df * 16 + li] = (f16)(Oa[df][r] * inv);
    }
  }
}

extern "C" void kernel_launch(void* const* d_in, const int* in_sizes, int n_in,
                              void* d_out, int out_size, void* d_ws, size_t ws_size,
                              hipStream_t stream) {
  (void)in_sizes; (void)n_in; (void)out_size; (void)ws_size;
  const float* x = (const float*)d_in[0];
  const float* Wq = (const float*)d_in[1];
  const float* Wk = (const float*)d_in[2];
  const float* Wv = (const float*)d_in[3];
  const float* Wout = (const float*)d_in[4];
  const float* ascale = (const float*)d_in[5];

  char* ws = (char*)d_ws;
  f16* x16 = (f16*)(ws);                       // 16 MB
  f16* WoutT = (f16*)(ws + (16ull << 20));     // 8 MB
  f16* WqT = (f16*)(ws + (24ull << 20));       // 8 MB
  f16* WkT = (f16*)(ws + (32ull << 20));       // 8 MB
  f16* WvT = (f16*)(ws + (40ull << 20));       // 8 MB
  f16* qh = (f16*)(ws + (48ull << 20));        // 16 MB  (B,H,L,Dh)
  f16* kh = (f16*)(ws + (64ull << 20));        // 16 MB
  f16* vT = (f16*)(ws + (80ull << 20));        // 16 MB  (B,H,Dh,L)
  f16* attO = (f16*)(ws + (24ull << 20));      // 16 MB, aliases WqT/WkT (dead by then)

  k_cast<<<dim3(4096), dim3(256), 0, stream>>>(x, x16, 1048576);
  k_transpose4<<<dim3(64, 64, 4), dim3(32, 8), 0, stream>>>(Wq, Wk, Wv, Wout,
                                                            WqT, WkT, WvT, WoutT);
  k_gemm8_qkv<<<dim3(384), dim3(512), 0, stream>>>(x16, WqT, WkT, WvT, qh, kh, vT);
  k_rope_norm<<<dim3(32768), dim3(256), 0, stream>>>(qh, kh);
  k_flash<<<dim3(16, 32), dim3(256), 0, stream>>>(qh, kh, vT, attO, ascale);
  k_gemm8_out<<<dim3(256), dim3(512), 0, stream>>>(attO, WoutT, (float*)d_out);
}

// Round 5
// 423.922 us; speedup vs baseline: 1.3785x; 1.0276x over previous
//
#include <hip/hip_runtime.h>
#include <hip/hip_fp16.h>

#define B_ 2
#define L_ 2048
#define D_ 2048
#define H_ 16
#define DH_ 128

typedef _Float16 f16;
typedef _Float16 f16x8 __attribute__((ext_vector_type(8)));
typedef _Float16 f16x4 __attribute__((ext_vector_type(4)));
typedef _Float16 f16x2 __attribute__((ext_vector_type(2)));
typedef float f32x4 __attribute__((ext_vector_type(4)));

__device__ __forceinline__ void gload_lds16(const void* g, void* l) {
  __builtin_amdgcn_global_load_lds(
      (__attribute__((address_space(1))) void*)(void*)g,
      (__attribute__((address_space(3))) void*)l, 16, 0, 0);
}

template <int N>
__device__ __forceinline__ void waitcnt_vm() {
  if constexpr (N == 0) asm volatile("s_waitcnt vmcnt(0)" ::: "memory");
  else if constexpr (N == 4) asm volatile("s_waitcnt vmcnt(4)" ::: "memory");
  else if constexpr (N == 6) asm volatile("s_waitcnt vmcnt(6)" ::: "memory");
  else if constexpr (N == 8) asm volatile("s_waitcnt vmcnt(8)" ::: "memory");
}

__device__ __forceinline__ float rmax16(float v) {
  v = fmaxf(v, __shfl_xor(v, 1));
  v = fmaxf(v, __shfl_xor(v, 2));
  v = fmaxf(v, __shfl_xor(v, 4));
  v = fmaxf(v, __shfl_xor(v, 8));
  return v;
}
__device__ __forceinline__ float rsum16(float v) {
  v += __shfl_xor(v, 1);
  v += __shfl_xor(v, 2);
  v += __shfl_xor(v, 4);
  v += __shfl_xor(v, 8);
  return v;
}

// ---------------- kernel 1: cast x fp32 -> fp16 ----------------
__global__ __launch_bounds__(256) void k_cast(const float* __restrict__ in,
                                              f16* __restrict__ out, int n8) {
  int i = blockIdx.x * blockDim.x + threadIdx.x;
  if (i >= n8) return;
  const float4* p = (const float4*)in + (size_t)i * 2;
  float4 a = p[0], b = p[1];
  f16x8 o;
  o[0] = (f16)a.x; o[1] = (f16)a.y; o[2] = (f16)a.z; o[3] = (f16)a.w;
  o[4] = (f16)b.x; o[5] = (f16)b.y; o[6] = (f16)b.z; o[7] = (f16)b.w;
  *((f16x8*)out + i) = o;
}

// ------- kernel 2: transpose+cast 2048x2048 fp32 -> fp16 (N x K) -------
__global__ __launch_bounds__(256) void k_transpose4(
    const float* __restrict__ W0, const float* __restrict__ W1,
    const float* __restrict__ W2, const float* __restrict__ W3,
    f16* __restrict__ T0, f16* __restrict__ T1, f16* __restrict__ T2,
    f16* __restrict__ T3) {
  int z = blockIdx.z;
  const float* src = (z == 0) ? W0 : (z == 1) ? W1 : (z == 2) ? W2 : W3;
  f16* dst = (z == 0) ? T0 : (z == 1) ? T1 : (z == 2) ? T2 : T3;
  __shared__ float tile[32][33];
  int tx = threadIdx.x, ty = threadIdx.y;
  int x = blockIdx.x * 32 + tx;
  int y0 = blockIdx.y * 32;
#pragma unroll
  for (int i = 0; i < 4; ++i)
    tile[ty + i * 8][tx] = src[(size_t)(y0 + ty + i * 8) * 2048 + x];
  __syncthreads();
  int ox = y0 + tx;
  int oy0 = blockIdx.x * 32;
#pragma unroll
  for (int i = 0; i < 4; ++i)
    dst[(size_t)(oy0 + ty + i * 8) * 2048 + ox] = (f16)tile[tx][ty + i * 8];
}

// stage NL*512 16B-chunks: linear LDS dest, inverse-swizzled global source.
// global rows are 4096 B (K=2048 f16); LDS rows are 128 B (64 f16, 8 chunks).
template <int NL>
__device__ __forceinline__ void stage_slot(const char* __restrict__ src,
                                           char* dst, int tid) {
#pragma unroll
  for (int j = 0; j < NL; ++j) {
    int ci = j * 512 + tid;
    int row = ci >> 3;
    int sc = (ci & 7) ^ (row & 7);
    gload_lds16(src + (size_t)row * 4096 + sc * 16, dst + ci * 16);
  }
}

// ======== qkv GEMM: BM=128, BN=384 (fused q|k|v), BK=64, 8 waves, 3 phases ========
__global__ __launch_bounds__(512, 2) void k_gemm8_qkv(
    const f16* __restrict__ x16, const f16* __restrict__ WT /* [6144][2048] */,
    f16* __restrict__ qh, f16* __restrict__ kh, f16* __restrict__ vTo) {
  constexpr int ABYTES = 128 * 128;          // 16 KiB
  constexpr int BUFB = ABYTES + 384 * 128;   // 64 KiB
  constexpr int nt = 32;
  __shared__ alignas(16) char lds[2 * BUFB]; // 128 KiB

  const int pb = blockIdx.x;                  // 0..511 (512 % 8 == 0)
  const int lgc = (pb & 7) * 64 + (pb >> 3);  // bijective XCD chunking
  const int m0 = (lgc >> 4) * 128;            // 32 m-tiles
  const int n0 = (lgc & 15) * 384;            // 16 n-tiles

  const int tid = threadIdx.x;
  const int lane = tid & 63, w = tid >> 6;
  const int wr = w >> 2, wc = w & 3;          // 2M x 4N waves
  const int li = lane & 15, lg = lane >> 4;

  const char* Ab = (const char*)x16 + (size_t)m0 * 4096;
  const char* Bb = (const char*)WT + (size_t)n0 * 4096;

  f32x4 acc[4][6] = {};

  // prologue: tiles 0,1
#pragma unroll
  for (int t = 0; t < 2; ++t) {
    char* bA = lds + t * BUFB;
    stage_slot<2>(Ab + t * 128, bA, tid);
    stage_slot<6>(Bb + t * 128, bA + ABYTES, tid);
  }
  waitcnt_vm<8>();
  __builtin_amdgcn_s_barrier();

  const int sx = (li & 7);  // row&7 for all frag rows (row == li mod 8)

#pragma unroll 1
  for (int u = 0; u < nt; ++u) {
    const int c = u & 1;
    char* bufA = lds + c * BUFB;
    char* bufB = bufA + ABYTES;
    char* oA = lds + (c ^ 1) * BUFB;
    f16x8 af[4][2], bf[6][2];

    // ---- phase 0: read A frags + B frags nc 0,1; stage A(u+1); MFMA nc 0,1 ----
#pragma unroll
    for (int mr = 0; mr < 4; ++mr) {
      int rb = (wr * 64 + mr * 16 + li) * 128;
      af[mr][0] = *(const f16x8*)(bufA + rb + ((lg ^ sx) << 4));
      af[mr][1] = *(const f16x8*)(bufA + rb + (((4 + lg) ^ sx) << 4));
    }
#pragma unroll
    for (int nc = 0; nc < 2; ++nc) {
      int rb = (wc * 96 + nc * 16 + li) * 128;
      bf[nc][0] = *(const f16x8*)(bufB + rb + ((lg ^ sx) << 4));
      bf[nc][1] = *(const f16x8*)(bufB + rb + (((4 + lg) ^ sx) << 4));
    }
    if (u >= 1 && u + 1 < nt) stage_slot<2>(Ab + (size_t)(u + 1) * 128, oA, tid);
    __builtin_amdgcn_s_barrier();
    asm volatile("s_waitcnt lgkmcnt(0)" ::: "memory");
    __builtin_amdgcn_sched_barrier(0);
    __builtin_amdgcn_s_setprio(1);
#pragma unroll
    for (int mr = 0; mr < 4; ++mr)
#pragma unroll
      for (int nc = 0; nc < 2; ++nc) {
        acc[mr][nc] = __builtin_amdgcn_mfma_f32_16x16x32_f16(af[mr][0], bf[nc][0],
                                                             acc[mr][nc], 0, 0, 0);
        acc[mr][nc] = __builtin_amdgcn_mfma_f32_16x16x32_f16(af[mr][1], bf[nc][1],
                                                             acc[mr][nc], 0, 0, 0);
      }
    __builtin_amdgcn_s_setprio(0);
    __builtin_amdgcn_s_barrier();

    // ---- phase 1: read B frags nc 2..5; MFMA nc 2,3 ----
#pragma unroll
    for (int nc = 2; nc < 6; ++nc) {
      int rb = (wc * 96 + nc * 16 + li) * 128;
      bf[nc][0] = *(const f16x8*)(bufB + rb + ((lg ^ sx) << 4));
      bf[nc][1] = *(const f16x8*)(bufB + rb + (((4 + lg) ^ sx) << 4));
    }
    __builtin_amdgcn_s_barrier();
    asm volatile("s_waitcnt lgkmcnt(0)" ::: "memory");
    __builtin_amdgcn_sched_barrier(0);
    __builtin_amdgcn_s_setprio(1);
#pragma unroll
    for (int mr = 0; mr < 4; ++mr)
#pragma unroll
      for (int nc = 2; nc < 4; ++nc) {
        acc[mr][nc] = __builtin_amdgcn_mfma_f32_16x16x32_f16(af[mr][0], bf[nc][0],
                                                             acc[mr][nc], 0, 0, 0);
        acc[mr][nc] = __builtin_amdgcn_mfma_f32_16x16x32_f16(af[mr][1], bf[nc][1],
                                                             acc[mr][nc], 0, 0, 0);
      }
    __builtin_amdgcn_s_setprio(0);
    __builtin_amdgcn_s_barrier();

    // ---- phase 2: stage B(u+2) into current bufB (reads done); MFMA nc 4,5 ----
    if (u + 2 < nt) stage_slot<6>(Bb + (size_t)(u + 2) * 128, bufB, tid);
    if (u + 2 < nt) waitcnt_vm<6>();
    else if (u + 1 < nt) waitcnt_vm<0>();
    __builtin_amdgcn_s_barrier();
    __builtin_amdgcn_sched_barrier(0);
    __builtin_amdgcn_s_setprio(1);
#pragma unroll
    for (int mr = 0; mr < 4; ++mr)
#pragma unroll
      for (int nc = 4; nc < 6; ++nc) {
        acc[mr][nc] = __builtin_amdgcn_mfma_f32_16x16x32_f16(af[mr][0], bf[nc][0],
                                                             acc[mr][nc], 0, 0, 0);
        acc[mr][nc] = __builtin_amdgcn_mfma_f32_16x16x32_f16(af[mr][1], bf[nc][1],
                                                             acc[mr][nc], 0, 0, 0);
      }
    __builtin_amdgcn_s_setprio(0);
    __builtin_amdgcn_s_barrier();
  }

  // epilogue: n -> (z, h, dh); z<2 scalar head-major, z==2 v-transposed f16x4
#pragma unroll
  for (int mr = 0; mr < 4; ++mr) {
    int mb = m0 + wr * 64 + mr * 16 + lg * 4;   // multiple of 4
    int b = mb >> 11, l = mb & 2047;
#pragma unroll
    for (int nc = 0; nc < 6; ++nc) {
      int n = n0 + wc * 96 + nc * 16 + li;
      int z = n >> 11, n2 = n & 2047;
      int h = n2 >> 7, dh = n2 & 127;
      if (z < 2) {
        f16* out = (z == 0) ? qh : kh;
#pragma unroll
        for (int r2 = 0; r2 < 4; ++r2) {
          int m = mb + r2;
          out[(((size_t)(b * 16 + h) * 2048 + (m & 2047)) << 7) + dh] =
              (f16)acc[mr][nc][r2];
        }
      } else {
        f16x4 v4;
#pragma unroll
        for (int r2 = 0; r2 < 4; ++r2) v4[r2] = (f16)acc[mr][nc][r2];
        *(f16x4*)(vTo + ((size_t)(b * 16 + h) * 128 + dh) * 2048 + l) = v4;
      }
    }
  }
}

// ======== 4-phase GEMM core for gemm_out (round-3 structure) ========
template <int BM>
__device__ __forceinline__ void gemm8_core(const f16* __restrict__ A,
                                           const f16* __restrict__ BT,
                                           char* lds, int m0, int n0,
                                           f32x4 (&acc)[BM / 32][4]) {
  constexpr int WRS = BM / 2;
  constexpr int MR = BM / 32;
  constexpr int MPP = MR / 4;
  constexpr int ALOADS = BM / 128;
  constexpr int LPT = 2 * ALOADS + 4;
  constexpr int ABYTES = BM * 128;
  constexpr int BUFB = ABYTES + 32768;
  constexpr int nt = 32;

  const int tid = threadIdx.x;
  const int lane = tid & 63, w = tid >> 6;
  const int wr = w >> 2, wc = w & 3;
  const int li = lane & 15, lg = lane >> 4;

  const char* Ab = (const char*)A + (size_t)m0 * 4096;
  const char* Bb = (const char*)BT + (size_t)n0 * 4096;

  const int aoff0 = (wr * WRS + li) * 128 + ((lg) ^ (li & 7)) * 16;
  const int aoff1 = (wr * WRS + li) * 128 + ((4 + lg) ^ (li & 7)) * 16;
  const int boff0 = (wc * 64 + li) * 128 + ((lg) ^ (li & 7)) * 16;
  const int boff1 = (wc * 64 + li) * 128 + ((4 + lg) ^ (li & 7)) * 16;

#pragma unroll
  for (int t = 0; t < 2; ++t) {
    char* bA = lds + t * BUFB;
    stage_slot<ALOADS>(Ab + t * 128, bA, tid);
    stage_slot<ALOADS>(Ab + (size_t)WRS * 4096 + t * 128, bA + (size_t)WRS * 128, tid);
    stage_slot<2>(Bb + t * 128, bA + ABYTES, tid);
    stage_slot<2>(Bb + (size_t)128 * 4096 + t * 128, bA + ABYTES + 128 * 128, tid);
  }
  waitcnt_vm<LPT>();
  __builtin_amdgcn_s_barrier();

#pragma unroll 1
  for (int u = 0; u < nt; ++u) {
    const int c = u & 1;
    char* bufA = lds + c * BUFB;
    char* bufB = bufA + ABYTES;
    char* oA = lds + (c ^ 1) * BUFB;
    f16x8 bf[4][2];
#pragma unroll
    for (int p = 0; p < 4; ++p) {
      f16x8 af[MPP][2];
#pragma unroll
      for (int i = 0; i < MPP; ++i) {
        af[i][0] = *(const f16x8*)(bufA + aoff0 + (p * MPP + i) * 2048);
        af[i][1] = *(const f16x8*)(bufA + aoff1 + (p * MPP + i) * 2048);
      }
      if (p == 0) {
#pragma unroll
        for (int nc = 0; nc < 4; ++nc) {
          bf[nc][0] = *(const f16x8*)(bufB + boff0 + nc * 2048);
          bf[nc][1] = *(const f16x8*)(bufB + boff1 + nc * 2048);
        }
      }
      if (p == 0 && u >= 1 && u + 1 < nt)
        stage_slot<ALOADS>(Ab + (size_t)(u + 1) * 128, oA, tid);
      if (p == 1 && u >= 1 && u + 1 < nt)
        stage_slot<ALOADS>(Ab + (size_t)WRS * 4096 + (size_t)(u + 1) * 128,
                           oA + (size_t)WRS * 128, tid);
      if (p == 2 && u + 2 < nt)
        stage_slot<2>(Bb + (size_t)(u + 2) * 128, bufB, tid);
      if (p == 3 && u + 2 < nt)
        stage_slot<2>(Bb + (size_t)128 * 4096 + (size_t)(u + 2) * 128,
                      bufB + 128 * 128, tid);
      if (p == 3) {
        if (u + 2 < nt) waitcnt_vm<4>();
        else if (u + 1 < nt) waitcnt_vm<0>();
      }
      __builtin_amdgcn_s_barrier();
      asm volatile("s_waitcnt lgkmcnt(0)" ::: "memory");
      __builtin_amdgcn_sched_barrier(0);
      __builtin_amdgcn_s_setprio(1);
#pragma unroll
      for (int i = 0; i < MPP; ++i)
#pragma unroll
        for (int nc = 0; nc < 4; ++nc) {
          acc[p * MPP + i][nc] = __builtin_amdgcn_mfma_f32_16x16x32_f16(
              af[i][0], bf[nc][0], acc[p * MPP + i][nc], 0, 0, 0);
          acc[p * MPP + i][nc] = __builtin_amdgcn_mfma_f32_16x16x32_f16(
              af[i][1], bf[nc][1], acc[p * MPP + i][nc], 0, 0, 0);
        }
      __builtin_amdgcn_s_setprio(0);
      __builtin_amdgcn_s_barrier();
    }
  }
}

// --------- kernel 6: output projection (BM=128/BN=256 -> 256 blocks) ---------
__global__ __launch_bounds__(512, 2) void k_gemm8_out(
    const f16* __restrict__ A, const f16* __restrict__ WoutT,
    float* __restrict__ out) {
  __shared__ alignas(16) char lds[2 * (128 * 128 + 32768)];  // 96 KiB
  const int pb = blockIdx.x;
  const int lgc = (pb & 7) * 32 + (pb >> 3);
  const int m0 = (lgc >> 3) * 128, n0 = (lgc & 7) * 256;
  f32x4 acc[4][4] = {};
  gemm8_core<128>(A, WoutT, lds, m0, n0, acc);

  const int lane = threadIdx.x & 63, w = threadIdx.x >> 6;
  const int wr = w >> 2, wc = w & 3, li = lane & 15, lg = lane >> 4;
#pragma unroll
  for (int mr = 0; mr < 4; ++mr) {
#pragma unroll
    for (int nc = 0; nc < 4; ++nc) {
      int n = n0 + wc * 64 + nc * 16 + li;
#pragma unroll
      for (int r2 = 0; r2 < 4; ++r2) {
        int m = m0 + wr * 64 + mr * 16 + lg * 4 + r2;
        out[(size_t)m * 2048 + n] = acc[mr][nc][r2];
      }
    }
  }
}

// ---------------- kernel 4: RoPE + L2 normalize, in place on qh/kh ----------------
__global__ __launch_bounds__(256) void k_rope_norm(f16* __restrict__ qh,
                                                   f16* __restrict__ kh) {
  int gid = blockIdx.x * 4 + (threadIdx.x >> 6);
  int lane = threadIdx.x & 63;
  int which = gid >> 16;
  int r = gid & 65535;
  int l = r & 2047;
  f16* base = (which ? kh : qh) + (size_t)r * 128;
  f16x2 xv = *(f16x2*)(base + lane * 2);
  float x0 = (float)xv[0], x1 = (float)xv[1];
  float invf = exp2f(-(float)lane * 0.29580575889569f);
  float ang = (float)l * invf;
  float s, c;
  sincosf(ang, &s, &c);
  float y0 = x0 * c - x1 * s;
  float y1 = x1 * c + x0 * s;
  float ss = y0 * y0 + y1 * y1;
  ss += __shfl_xor(ss, 1);  ss += __shfl_xor(ss, 2);
  ss += __shfl_xor(ss, 4);  ss += __shfl_xor(ss, 8);
  ss += __shfl_xor(ss, 16); ss += __shfl_xor(ss, 32);
  float inv = 1.0f / (sqrtf(ss) + 1e-6f);
  f16x2 o;
  o[0] = (f16)(y0 * inv);
  o[1] = (f16)(y1 * inv);
  *(f16x2*)(base + lane * 2) = o;
}

// ---------------- kernel 5: flash attention, gload_lds + swizzle + dbuf ----------------
// 32 q-tiles of 64 rows; block handles q-tiles {bx, 31-bx}. 4 waves x 16 q-rows.
__global__ __launch_bounds__(256) void k_flash(
    const f16* __restrict__ qh, const f16* __restrict__ kh,
    const f16* __restrict__ vT, f16* __restrict__ attO,
    const float* __restrict__ ascale_p) {
  const int bh = blockIdx.y;
  const int tid = threadIdx.x, lane = tid & 63, w = tid >> 6;
  const int li = lane & 15, lg = lane >> 4;
  const float csc = ascale_p[0] * 1.44269504088896f;
  const float thr = 8.0f / csc;

  __shared__ alignas(16) f16 Ks[2][64 * 128];   // swizzled 16B chunks, 16/row
  __shared__ alignas(16) f16 Vs[2][128 * 64];   // swizzled 16B chunks, 8/row
  __shared__ alignas(16) f16 Ps[4][16 * 72];

  const f16* qb = qh + (size_t)bh * 2048 * 128;
  const char* kbB = (const char*)(kh + (size_t)bh * 2048 * 128);
  const char* vbB = (const char*)(vT + (size_t)bh * 128 * 2048);
  const int b = bh >> 4, h = bh & 15;
  const int sx = li & 7;

  // stage K/V tile kt into buffer bsel: linear LDS dest, inv-swizzled source
  auto stage_tile = [&](int kt, int bsel) {
    char* Kd = (char*)Ks[bsel];
    char* Vd = (char*)Vs[bsel];
    const char* ksrc = kbB + (size_t)kt * 64 * 256;   // 64 rows x 256 B
    const char* vsrc = vbB + (size_t)kt * 128;        // col offset k0*2 B
#pragma unroll
    for (int j = 0; j < 4; ++j) {
      int ci = j * 256 + tid;
      int row = ci >> 4, sc = (ci & 15) ^ (row & 7);
      gload_lds16(ksrc + (size_t)row * 256 + sc * 16, Kd + ci * 16);
      int row2 = ci >> 3, sc2 = (ci & 7) ^ (row2 & 7);
      gload_lds16(vsrc + (size_t)row2 * 4096 + sc2 * 16, Vd + ci * 16);
    }
  };

#pragma unroll 1
  for (int ti = 0; ti < 2; ++ti) {
    const int t = ti ? (31 - (int)blockIdx.x) : (int)blockIdx.x;
    const int qw = t * 64 + w * 16;

    f16x8 Qr[4];
#pragma unroll
    for (int ks = 0; ks < 4; ++ks)
      Qr[ks] = *(const f16x8*)(qb + (size_t)(qw + li) * 128 + ks * 32 + lg * 8);

    f32x4 Oa[8] = {};
    float mrow[4], lrow[4];
#pragma unroll
    for (int r = 0; r < 4; ++r) { mrow[r] = -1e30f; lrow[r] = 0.0f; }

    stage_tile(0, 0);
    waitcnt_vm<0>();
    __syncthreads();

#pragma unroll 1
    for (int kt = 0; kt <= t; ++kt) {
      const int c = kt & 1;
      if (kt + 1 <= t) stage_tile(kt + 1, c ^ 1);   // prefetch next tile
      const char* Kb = (const char*)Ks[c];
      const char* Vb = (const char*)Vs[c];

      // S = Q K^T
      f32x4 Sa[4] = {};
      __builtin_amdgcn_s_setprio(1);
#pragma unroll
      for (int ks = 0; ks < 4; ++ks) {
        f16x8 kf4[4];
#pragma unroll
        for (int kf = 0; kf < 4; ++kf) {
          int cc = (ks * 4 + lg) ^ sx;
          kf4[kf] = *(const f16x8*)(Kb + (kf * 16 + li) * 256 + cc * 16);
        }
#pragma unroll
        for (int kf = 0; kf < 4; ++kf)
          Sa[kf] = __builtin_amdgcn_mfma_f32_16x16x32_f16(Qr[ks], kf4[kf],
                                                          Sa[kf], 0, 0, 0);
      }
      __builtin_amdgcn_s_setprio(0);

      if (kt == t) {  // diagonal: causal mask
#pragma unroll
        for (int kf = 0; kf < 4; ++kf)
#pragma unroll
          for (int r = 0; r < 4; ++r) {
            int qq = qw + lg * 4 + r;
            int kk = t * 64 + kf * 16 + li;
            if (kk > qq) Sa[kf][r] = -1e30f;
          }
      }

      float vmax[4];
      bool need = false;
#pragma unroll
      for (int r = 0; r < 4; ++r) {
        float v = fmaxf(fmaxf(Sa[0][r], Sa[1][r]), fmaxf(Sa[2][r], Sa[3][r]));
        v = rmax16(v);
        vmax[r] = v;
        need |= (v > mrow[r] + thr);
      }
      if (__any(need)) {
#pragma unroll
        for (int r = 0; r < 4; ++r) {
          float mnew = fmaxf(mrow[r], vmax[r]);
          float sc = exp2f(csc * (mrow[r] - mnew));
          mrow[r] = mnew;
          lrow[r] *= sc;
#pragma unroll
          for (int df = 0; df < 8; ++df) Oa[df][r] *= sc;
        }
      }
#pragma unroll
      for (int r = 0; r < 4; ++r) {
        float rs = 0.0f;
#pragma unroll
        for (int kf = 0; kf < 4; ++kf) {
          float p = exp2f(csc * (Sa[kf][r] - mrow[r]));
          Sa[kf][r] = p;
          rs += p;
        }
        rs = rsum16(rs);
        lrow[r] += rs;
      }

      // P -> LDS (per-wave), then PV
      f16* Pw = &Ps[w][0];
#pragma unroll
      for (int kf = 0; kf < 4; ++kf)
#pragma unroll
        for (int r = 0; r < 4; ++r)
          Pw[(lg * 4 + r) * 72 + kf * 16 + li] = (f16)Sa[kf][r];
      asm volatile("s_waitcnt lgkmcnt(0)" ::: "memory");
      __builtin_amdgcn_sched_barrier(0);
      __builtin_amdgcn_s_setprio(1);
#pragma unroll
      for (int k2 = 0; k2 < 2; ++k2) {
        f16x8 pa, vfr[8];
        pa = *(const f16x8*)(Pw + li * 72 + k2 * 32 + lg * 8);
#pragma unroll
        for (int df = 0; df < 8; ++df) {
          int cc = (k2 * 4 + lg) ^ sx;
          vfr[df] = *(const f16x8*)(Vb + (df * 16 + li) * 128 + cc * 16);
        }
#pragma unroll
        for (int df = 0; df < 8; ++df)
          Oa[df] = __builtin_amdgcn_mfma_f32_16x16x32_f16(pa, vfr[df],
                                                          Oa[df], 0, 0, 0);
      }
      __builtin_amdgcn_s_setprio(0);
      waitcnt_vm<0>();   // prefetched tile landed (issued ~full iter ago)
      __syncthreads();
    }

    // epilogue: O /= l, write (B,L,H*Dh) fp16
#pragma unroll
    for (int r = 0; r < 4; ++r) {
      float inv = 1.0f / lrow[r];
      int q = qw + lg * 4 + r;
      f16* orow = attO + (size_t)(b * 2048 + q) * 2048 + h * 128;
#pragma unroll
      for (int df = 0; df < 8; ++df)
        orow[df * 16 + li] = (f16)(Oa[df][r] * inv);
    }
    __syncthreads();   // all reads done before next ti re-stages buf 0
  }
}

extern "C" void kernel_launch(void* const* d_in, const int* in_sizes, int n_in,
                              void* d_out, int out_size, void* d_ws, size_t ws_size,
                              hipStream_t stream) {
  (void)in_sizes; (void)n_in; (void)out_size; (void)ws_size;
  const float* x = (const float*)d_in[0];
  const float* Wq = (const float*)d_in[1];
  const float* Wk = (const float*)d_in[2];
  const float* Wv = (const float*)d_in[3];
  const float* Wout = (const float*)d_in[4];
  const float* ascale = (const float*)d_in[5];

  char* ws = (char*)d_ws;
  f16* x16 = (f16*)(ws);                       // 16 MB
  f16* WoutT = (f16*)(ws + (16ull << 20));     // 8 MB
  f16* WqT = (f16*)(ws + (24ull << 20));       // 8 MB, first third of [6144][2048]
  f16* WkT = (f16*)(ws + (32ull << 20));       // 8 MB, second third (contiguous)
  f16* WvT = (f16*)(ws + (40ull << 20));       // 8 MB, last third (contiguous)
  f16* qh = (f16*)(ws + (48ull << 20));        // 16 MB  (B,H,L,Dh)
  f16* kh = (f16*)(ws + (64ull << 20));        // 16 MB
  f16* vT = (f16*)(ws + (80ull << 20));        // 16 MB  (B,H,Dh,L)
  f16* attO = (f16*)(ws + (24ull << 20));      // 16 MB, aliases WqT/WkT (dead by then)

  k_cast<<<dim3(4096), dim3(256), 0, stream>>>(x, x16, 1048576);
  k_transpose4<<<dim3(64, 64, 4), dim3(32, 8), 0, stream>>>(Wq, Wk, Wv, Wout,
                                                            WqT, WkT, WvT, WoutT);
  k_gemm8_qkv<<<dim3(512), dim3(512), 0, stream>>>(x16, WqT, qh, kh, vT);
  k_rope_norm<<<dim3(32768), dim3(256), 0, stream>>>(qh, kh);
  k_flash<<<dim3(16, 32), dim3(256), 0, stream>>>(qh, kh, vT, attO, ascale);
  k_gemm8_out<<<dim3(256), dim3(512), 0, stream>>>(attO, WoutT, (float*)d_out);
}